// Round 1
// baseline (426.229 us; speedup 1.0000x reference)
//
#include <hip/hip_runtime.h>
#include <stdint.h>

#define D_MODEL 2048
#define N_HEADS 16
#define HEAD_D  128
#define BATCH   2
#define SEQ     2048
#define MTOT    (BATCH*SEQ)   // 4096

typedef __bf16 bf16x8 __attribute__((ext_vector_type(8)));
typedef float  f32x4  __attribute__((ext_vector_type(4)));
typedef unsigned short u16x8 __attribute__((ext_vector_type(8)));

__device__ __forceinline__ unsigned short f2bf(float f) {
  unsigned u = __builtin_bit_cast(unsigned, f);
  u += 0x7fffu + ((u >> 16) & 1u);
  return (unsigned short)(u >> 16);
}

__device__ __forceinline__ bf16x8 ld_frag(const unsigned short* p) {
  u16x8 raw = *(const u16x8*)p;
  return __builtin_bit_cast(bf16x8, raw);
}

__device__ __forceinline__ void gload16(const void* g, void* lds) {
  __builtin_amdgcn_global_load_lds(
      (const __attribute__((address_space(1))) unsigned int*)g,
      (__attribute__((address_space(3))) unsigned int*)lds, 16, 0, 0);
}

// ---------------- fp32 -> bf16 conversion (16B/lane) ----------------
__global__ __launch_bounds__(256) void f32_to_bf16_k(const float* __restrict__ in,
                                                     unsigned short* __restrict__ out,
                                                     int n8) {
  int i = blockIdx.x * 256 + threadIdx.x;
  if (i >= n8) return;
  const float4* p = (const float4*)in + (size_t)i * 2;
  float4 a = p[0], b = p[1];
  u16x8 o;
  o[0] = f2bf(a.x); o[1] = f2bf(a.y); o[2] = f2bf(a.z); o[3] = f2bf(a.w);
  o[4] = f2bf(b.x); o[5] = f2bf(b.y); o[6] = f2bf(b.z); o[7] = f2bf(b.w);
  *((u16x8*)out + i) = o;
}

// ---------------- GEMM: C = A(MxK) * B(NxK)^T, bf16 in, fp32 acc ----------------
// MODE 0: C fp32 row-major (MxN).  MODE 1: C bf16 written to (B,H,T,D) layout.
template<int MODE>
__global__ __launch_bounds__(256) void gemm_bt(const unsigned short* __restrict__ A,
                                               const unsigned short* __restrict__ B,
                                               void* __restrict__ C,
                                               int M, int N, int K) {
  __shared__ __align__(16) unsigned short As[128 * 32];
  __shared__ __align__(16) unsigned short Bs[128 * 32];
  const int tid  = threadIdx.x;
  const int lane = tid & 63;
  const int w    = tid >> 6;
  const int wr   = w >> 1, wc = w & 1;
  const int brow = blockIdx.y * 128;
  const int bcol = blockIdx.x * 128;

  // staging: 8 issues of 512 elems (1024B); wave w does issues w*2, w*2+1
  const int e0 = (w * 2) * 512 + lane * 8;
  const int e1 = (w * 2 + 1) * 512 + lane * 8;
  const int r0 = e0 >> 5, cc0 = e0 & 31;
  const int r1 = e1 >> 5, cc1 = e1 & 31;
  const unsigned short* Ap0 = A + (size_t)(brow + r0) * K + cc0;
  const unsigned short* Ap1 = A + (size_t)(brow + r1) * K + cc1;
  const unsigned short* Bp0 = B + (size_t)(bcol + r0) * K + cc0;
  const unsigned short* Bp1 = B + (size_t)(bcol + r1) * K + cc1;
  unsigned short* As0 = &As[(w * 2) * 512];
  unsigned short* As1 = &As[(w * 2 + 1) * 512];
  unsigned short* Bs0 = &Bs[(w * 2) * 512];
  unsigned short* Bs1 = &Bs[(w * 2 + 1) * 512];

  f32x4 acc[4][4] = {};
  const int la = lane & 15;
  const int lb = (lane >> 4) * 8;

  for (int kt = 0; kt < K; kt += 32) {
    gload16(Ap0 + kt, As0);
    gload16(Ap1 + kt, As1);
    gload16(Bp0 + kt, Bs0);
    gload16(Bp1 + kt, Bs1);
    __syncthreads();
    bf16x8 af[4], bfr[4];
#pragma unroll
    for (int m = 0; m < 4; ++m)
      af[m] = ld_frag(&As[(wr * 64 + m * 16 + la) * 32 + lb]);
#pragma unroll
    for (int n = 0; n < 4; ++n)
      bfr[n] = ld_frag(&Bs[(wc * 64 + n * 16 + la) * 32 + lb]);
#pragma unroll
    for (int m = 0; m < 4; ++m)
#pragma unroll
      for (int n = 0; n < 4; ++n)
        acc[m][n] = __builtin_amdgcn_mfma_f32_16x16x32_bf16(af[m], bfr[n], acc[m][n], 0, 0, 0);
    __syncthreads();
  }

  const int rowb = (lane >> 4) * 4;
#pragma unroll
  for (int m = 0; m < 4; ++m) {
#pragma unroll
    for (int n = 0; n < 4; ++n) {
      const int gcol = bcol + wc * 64 + n * 16 + la;
#pragma unroll
      for (int j = 0; j < 4; ++j) {
        const int grow = brow + wr * 64 + m * 16 + rowb + j;
        const float v = acc[m][n][j];
        if (MODE == 0) {
          ((float*)C)[(size_t)grow * N + gcol] = v;
        } else {
          const int bb = grow >> 11, tt = grow & (SEQ - 1);
          const int hh = gcol >> 7, dd = gcol & (HEAD_D - 1);
          ((unsigned short*)C)[(((size_t)bb * N_HEADS + hh) * SEQ + tt) * HEAD_D + dd] = f2bf(v);
        }
      }
    }
  }
}

// ---------------- V (BH,T,D) -> V^T (BH,D,T) ----------------
__global__ __launch_bounds__(256) void transpose_hd(const unsigned short* __restrict__ in,
                                                    unsigned short* __restrict__ out) {
  __shared__ __align__(16) unsigned short tile[64][80];
  const int t0 = blockIdx.x * 64;
  const int d0 = blockIdx.y * 64;
  const int bh = blockIdx.z;
  const size_t ibase = (size_t)bh * SEQ * HEAD_D;
  const size_t obase = (size_t)bh * HEAD_D * SEQ;
  const int tid = threadIdx.x;
#pragma unroll
  for (int s = 0; s < 2; ++s) {
    int idx = s * 256 + tid;
    int r = idx >> 3;
    int c = (idx & 7) * 8;
    *(u16x8*)&tile[r][c] = *(const u16x8*)&in[ibase + (size_t)(t0 + r) * HEAD_D + d0 + c];
  }
  __syncthreads();
#pragma unroll
  for (int s = 0; s < 2; ++s) {
    int idx = s * 256 + tid;
    int r = idx >> 3;
    int c = (idx & 7) * 8;
    u16x8 v;
#pragma unroll
    for (int j = 0; j < 8; ++j) v[j] = tile[c + j][r];
    *(u16x8*)&out[obase + (size_t)(d0 + r) * SEQ + t0 + c] = v;
  }
}

// ---------------- causal ALiBi flash attention ----------------
// Q,K: (BH,T,D) bf16.  VT: (BH,D,T) bf16.  O: (B,T,H*D) bf16.
// block = 256 thr (4 waves); wave owns 16 q-rows; QBLK=64, KVBLK=64.
__global__ __launch_bounds__(256) void attn_k(const unsigned short* __restrict__ Q,
                                              const unsigned short* __restrict__ K,
                                              const unsigned short* __restrict__ VT,
                                              unsigned short* __restrict__ O) {
  __shared__ __align__(16) unsigned short Ks[64 * HEAD_D];   // 16 KB, XOR-swizzled rows (256B)
  __shared__ __align__(16) unsigned short Vs[HEAD_D * 64];   // 16 KB, XOR-swizzled rows (128B)
  __shared__ __align__(16) unsigned short Ps[4][16 * 64];    // 8 KB, per-wave, swizzled

  const int tid = threadIdx.x, lane = tid & 63, w = tid >> 6;
  const int qt = blockIdx.x;
  const int h  = blockIdx.y;
  const int b  = blockIdx.z;
  const int bh = b * N_HEADS + h;
  const int q0 = qt * 64;

  const float slope = exp2f(-0.5f * (float)(h + 1));
  const float scale = 0.08838834764831845f;   // 1/sqrt(128)

  const int la = lane & 15;
  const int lq = lane >> 4;           // quarter-wave id

  // hoist Q fragments (wave's 16 rows x 128 cols)
  const int qrow = q0 + w * 16 + la;
  const size_t qbase = ((size_t)bh * SEQ + qrow) * HEAD_D + lq * 8;
  bf16x8 qf[4];
#pragma unroll
  for (int kk = 0; kk < 4; ++kk) qf[kk] = ld_frag(&Q[qbase + kk * 32]);

  f32x4 acc[8] = {};
  float mrow[4] = {-1e30f, -1e30f, -1e30f, -1e30f};
  float lrow[4] = {0.f, 0.f, 0.f, 0.f};

  const size_t kbase  = (size_t)bh * SEQ * HEAD_D;
  const size_t vtbase = (size_t)bh * HEAD_D * SEQ;

  const int ntiles = qt + 1;
  for (int it = 0; it < ntiles; ++it) {
    const int kv0 = it * 64;
    __syncthreads();   // prev iteration's LDS reads done
    // stage K tile [64][128] (16 issues, pre-swizzled global source, linear LDS dest)
#pragma unroll
    for (int s = 0; s < 4; ++s) {
      const int p = (w * 4 + s) * 1024 + lane * 16;   // linear byte pos in tile
      const int row = p >> 8;
      const int cb  = p & 255;
      const int col = (cb ^ ((row & 7) << 4)) >> 1;
      gload16(&K[kbase + (size_t)(kv0 + row) * HEAD_D + col], &Ks[(w * 4 + s) * 512]);
    }
    // stage VT tile [128][64]
#pragma unroll
    for (int s = 0; s < 4; ++s) {
      const int p = (w * 4 + s) * 1024 + lane * 16;
      const int d  = p >> 7;
      const int cb = p & 127;
      const int col = (cb ^ ((d & 7) << 4)) >> 1;
      gload16(&VT[vtbase + (size_t)d * SEQ + kv0 + col], &Vs[(w * 4 + s) * 512]);
    }
    __syncthreads();

    // S = Q K^T  (16 x 64 per wave)
    f32x4 sacc[4] = {};
#pragma unroll
    for (int c = 0; c < 4; ++c) {
#pragma unroll
      for (int kk = 0; kk < 4; ++kk) {
        const int row = c * 16 + la;
        const int cb  = kk * 64 + lq * 16;
        const int addr = row * 256 + (cb ^ ((row & 7) << 4));
        bf16x8 kf = ld_frag((const unsigned short*)((const char*)Ks + addr));
        sacc[c] = __builtin_amdgcn_mfma_f32_16x16x32_bf16(qf[kk], kf, sacc[c], 0, 0, 0);
      }
    }

    // online softmax (rows: lq*4+j; cols: c*16+la)
    const int qg = q0 + w * 16 + lq * 4;
    float pv[4][4];
    float corr[4];
#pragma unroll
    for (int j = 0; j < 4; ++j) {
      float mx = -1e30f;
#pragma unroll
      for (int c = 0; c < 4; ++c) {
        const int kvg = kv0 + c * 16 + la;
        const float sv = (kvg <= qg + j)
            ? fmaf(sacc[c][j], scale, slope * (float)(kvg - (qg + j)))
            : -1e30f;
        pv[c][j] = sv;
        mx = fmaxf(mx, sv);
      }
      mx = fmaxf(mx, __shfl_xor(mx, 1));
      mx = fmaxf(mx, __shfl_xor(mx, 2));
      mx = fmaxf(mx, __shfl_xor(mx, 4));
      mx = fmaxf(mx, __shfl_xor(mx, 8));
      const float nm = fmaxf(mrow[j], mx);
      const float cr = __expf(mrow[j] - nm);
      corr[j] = cr;
      float rs = 0.f;
#pragma unroll
      for (int c = 0; c < 4; ++c) {
        const float e = __expf(pv[c][j] - nm);
        pv[c][j] = e;
        rs += e;
      }
      rs += __shfl_xor(rs, 1);
      rs += __shfl_xor(rs, 2);
      rs += __shfl_xor(rs, 4);
      rs += __shfl_xor(rs, 8);
      lrow[j] = lrow[j] * cr + rs;
      mrow[j] = nm;
    }
#pragma unroll
    for (int n = 0; n < 8; ++n)
#pragma unroll
      for (int j = 0; j < 4; ++j) acc[n][j] *= corr[j];

    // write P (bf16) to per-wave swizzled LDS [16][64]
#pragma unroll
    for (int c = 0; c < 4; ++c) {
#pragma unroll
      for (int j = 0; j < 4; ++j) {
        const int row = lq * 4 + j;
        const int cbyte = (c * 16 + la) * 2;
        const int addr = row * 128 + (cbyte ^ ((row & 7) << 4));
        *(unsigned short*)((char*)Ps[w] + addr) = f2bf(pv[c][j]);
      }
    }
    __syncthreads();   // P visible for A-frag reads

    // O += P V
#pragma unroll
    for (int kk = 0; kk < 2; ++kk) {
      const int prow = la;
      const int pcb  = kk * 64 + lq * 16;
      const int paddr = prow * 128 + (pcb ^ ((prow & 7) << 4));
      bf16x8 pf = ld_frag((const unsigned short*)((const char*)Ps[w] + paddr));
#pragma unroll
      for (int n = 0; n < 8; ++n) {
        const int d = n * 16 + la;
        const int vcb = kk * 64 + lq * 16;
        const int vaddr = d * 128 + (vcb ^ ((d & 7) << 4));
        bf16x8 vf = ld_frag((const unsigned short*)((const char*)Vs + vaddr));
        acc[n] = __builtin_amdgcn_mfma_f32_16x16x32_bf16(pf, vf, acc[n], 0, 0, 0);
      }
    }
  }

  // epilogue: O[b][q][h*128+d] = acc/lsum
#pragma unroll
  for (int j = 0; j < 4; ++j) {
    const float inv = 1.0f / lrow[j];
    const int q = q0 + w * 16 + lq * 4 + j;
    const size_t obase = ((size_t)b * SEQ + q) * D_MODEL + (size_t)h * HEAD_D;
#pragma unroll
    for (int n = 0; n < 8; ++n) {
      const int d = n * 16 + la;
      O[obase + d] = f2bf(acc[n][j] * inv);
    }
  }
}

// ---------------- launcher ----------------
extern "C" void kernel_launch(void* const* d_in, const int* in_sizes, int n_in,
                              void* d_out, int out_size, void* d_ws, size_t ws_size,
                              hipStream_t stream) {
  (void)in_sizes; (void)n_in; (void)out_size; (void)ws_size;
  const float* x  = (const float*)d_in[0];
  const float* Wq = (const float*)d_in[1];
  const float* Wk = (const float*)d_in[2];
  const float* Wv = (const float*)d_in[3];
  const float* Wo = (const float*)d_in[4];

  char* ws = (char*)d_ws;
  unsigned short* xb = (unsigned short*)(ws + 0);          // 16 MiB
  unsigned short* wq = (unsigned short*)(ws + 16777216);   // 8 MiB
  unsigned short* wk = (unsigned short*)(ws + 25165824);   // 8 MiB
  unsigned short* wv = (unsigned short*)(ws + 33554432);   // 8 MiB
  unsigned short* wo = (unsigned short*)(ws + 41943040);   // 8 MiB
  unsigned short* q  = (unsigned short*)(ws + 50331648);   // 16 MiB
  unsigned short* k  = (unsigned short*)(ws + 67108864);   // 16 MiB
  unsigned short* v  = (unsigned short*)(ws + 83886080);   // 16 MiB
  unsigned short* vt = (unsigned short*)(ws + 16777216);   // aliases wq+wk (after their GEMMs)
  unsigned short* o  = (unsigned short*)(ws + 0);          // aliases xb (after QKV GEMMs)

  f32_to_bf16_k<<<4096, 256, 0, stream>>>(x,  xb, (MTOT * D_MODEL) / 8);
  f32_to_bf16_k<<<2048, 256, 0, stream>>>(Wq, wq, (D_MODEL * D_MODEL) / 8);
  f32_to_bf16_k<<<2048, 256, 0, stream>>>(Wk, wk, (D_MODEL * D_MODEL) / 8);
  f32_to_bf16_k<<<2048, 256, 0, stream>>>(Wv, wv, (D_MODEL * D_MODEL) / 8);
  f32_to_bf16_k<<<2048, 256, 0, stream>>>(Wo, wo, (D_MODEL * D_MODEL) / 8);

  dim3 gg(D_MODEL / 128, MTOT / 128);   // (16, 32)
  gemm_bt<1><<<gg, 256, 0, stream>>>(xb, wq, q, MTOT, D_MODEL, D_MODEL);
  gemm_bt<1><<<gg, 256, 0, stream>>>(xb, wk, k, MTOT, D_MODEL, D_MODEL);
  gemm_bt<1><<<gg, 256, 0, stream>>>(xb, wv, v, MTOT, D_MODEL, D_MODEL);

  transpose_hd<<<dim3(SEQ / 64, HEAD_D / 64, BATCH * N_HEADS), 256, 0, stream>>>(v, vt);

  attn_k<<<dim3(SEQ / 64, N_HEADS, BATCH), 256, 0, stream>>>(q, k, vt, o);

  gemm_bt<0><<<gg, 256, 0, stream>>>(o, wo, d_out, MTOT, D_MODEL, D_MODEL);
}